// Round 22
// baseline (263.254 us; speedup 1.0000x reference)
//
#include <hip/hip_runtime.h>
#include <math.h>

// PerceptronGlia r22: block-shared LDS weights, 2-layer double-buffer.
// r20 failed because it barriered EVERY layer and __syncthreads' implicit
// vmcnt(0) drain left the prefetch only ~half a layer of compute cover.
// r22: 2 layers per buffer, barrier per PAIR (193 vs 385), prefetch for
// the next pair issued at pair start -> ~1600cy cover. 256-thread blocks
// (4 waves x 2 rows = 8 rows) share each weight read via global_load_lds
// (chunk q goes to wave q&3). Per-wave math = r11's validated 2-row
// float2 state, K ladder 13..5 / 4..1, pk ops + ?: ELU (absmax 0.0156).

#define PAIRBUF 1152   // float4 per pair buffer (2 layers x NCmax=9 x 64)

// ---- packed-FP32 asm helpers (weight broadcast via op_sel) ----
template<int HI>
__device__ __forceinline__ float2 pk_mul_b(float2 a, float2 w) {
    float2 d;
    if constexpr (HI)
        asm("v_pk_mul_f32 %0, %1, %2 op_sel:[0,1] op_sel_hi:[1,1]"
            : "=v"(d) : "v"(a), "v"(w));
    else
        asm("v_pk_mul_f32 %0, %1, %2 op_sel_hi:[1,0]"
            : "=v"(d) : "v"(a), "v"(w));
    return d;
}
template<int HI>
__device__ __forceinline__ float2 pk_fma_b(float2 a, float2 w, float2 c) {
    float2 d;
    if constexpr (HI)
        asm("v_pk_fma_f32 %0, %1, %2, %3 op_sel:[0,1,0] op_sel_hi:[1,1,1]"
            : "=v"(d) : "v"(a), "v"(w), "v"(c));
    else
        asm("v_pk_fma_f32 %0, %1, %2, %3 op_sel_hi:[1,0,1]"
            : "=v"(d) : "v"(a), "v"(w), "v"(c));
    return d;
}
__device__ __forceinline__ float2 pk_mul2(float2 a, float2 b) {
    float2 d;
    asm("v_pk_mul_f32 %0, %1, %2" : "=v"(d) : "v"(a), "v"(b));
    return d;
}
__device__ __forceinline__ float vexp2(float x) {
    float d;
    asm("v_exp_f32 %0, %1" : "=v"(d) : "v"(x));
    return d;
}
__device__ __forceinline__ float elu_f(float a) {
    return a > 0.0f ? a : (__expf(a) - 1.0f);
}

// ---- async global->LDS, 16B per lane ----
__device__ __forceinline__ void gl2lds16(const float4* g, float4* l) {
    __builtin_amdgcn_global_load_lds(
        (const __attribute__((address_space(1))) unsigned int*)(const void*)g,
        (__attribute__((address_space(3))) unsigned int*)(void*)l, 16, 0, 0);
}

// ---- one slot of a scan layer, both rows packed; static recursion ----
template<int K, int I, int NW>
__device__ __forceinline__ void slot_run(float2 (&h)[K], const float2 (&w)[NW],
                                         float2 e0, float2 e1, float2 l2e) {
    if constexpr (I < K) {
        float2 x1, x2;
        if constexpr (I + 1 < K) x1 = h[I + 1]; else x1 = e0;
        if constexpr (I + 2 < K) x2 = h[I + 2];
        else if constexpr (I + 2 == K) x2 = e0;
        else x2 = e1;
        float2 acc = pk_mul_b<(3 * I + 2) & 1>(x2, w[(3 * I + 2) >> 1]);
        acc = pk_fma_b<(3 * I + 1) & 1>(x1, w[(3 * I + 1) >> 1], acc);
        acc = pk_fma_b<(3 * I) & 1>(h[I], w[(3 * I) >> 1], acc);
        float2 t = pk_mul2(acc, l2e);                 // a * log2(e)
        float ex = vexp2(t.x) - 1.0f;
        float ey = vexp2(t.y) - 1.0f;
        h[I].x = acc.x > 0.0f ? acc.x : ex;
        h[I].y = acc.y > 0.0f ? acc.y : ey;
        slot_run<K, I + 1, NW>(h, w, e0, e1, l2e);
    }
}

template<int K, int NW>
__device__ __forceinline__ void scan_layer_pk(float2 (&h)[K], const float2 (&w)[NW],
                                              float2 l2e) {
    float2 e0, e1;
    e0.x = __shfl_down(h[0].x, 1); e0.y = __shfl_down(h[0].y, 1);
    if constexpr (K >= 2) { e1.x = __shfl_down(h[1].x, 1); e1.y = __shfl_down(h[1].y, 1); }
    else                  { e1.x = __shfl_down(h[0].x, 2); e1.y = __shfl_down(h[0].y, 2); }
    slot_run<K, 0, NW>(h, w, e0, e1, l2e);
}

// ---- direct (register) weight load: NC float4 -> 2*NC float2 pairs ----
template<int NC>
__device__ __forceinline__ void load_wt2(float2 (&w)[2 * NC], const float4* __restrict__ Tp,
                                         int lr) {
#pragma unroll
    for (int c = 0; c < NC; ++c) {
        float4 v = Tp[(size_t)lr * (NC * 64) + c * 64];
        w[2 * c]     = make_float2(v.x, v.y);
        w[2 * c + 1] = make_float2(v.z, v.w);
    }
}

// ---- one layer computed from an LDS buffer (layer index li within pair) ----
template<int K, int NC>
__device__ __forceinline__ void layer_from_lds(float2 (&h)[K], const float4* buf,
                                               int li, int lane, float2 l2e) {
    const float4* wsrc = buf + li * (NC * 64);
    float2 wr[2 * NC];
#pragma unroll
    for (int c = 0; c < NC; ++c) {
        float4 v = wsrc[c * 64 + lane];               // ds_read_b128
        wr[2 * c]     = make_float2(v.x, v.y);
        wr[2 * c + 1] = make_float2(v.z, v.w);
    }
    scan_layer_pk<K>(h, wr, l2e);
}

// ---- staged scan phase, pair-wise double-buffer ----
// Entry: buf[cur] holds this phase's pair 0. Per pair: issue prefetch of the
// next pair (or the next phase's first pair, NNC2 chunks) into buf^1, compute
// 2 layers from buf[cur], __syncthreads (all waves' prefetches landed), flip.
template<int K, int NC, int NPAIRS, int NNC2>
__device__ __forceinline__ void scan_phase2(const float* __restrict__ Tph,
                                            const float* __restrict__ Tnext,
                                            int w, int lane,
                                            float2 (&h)[K], float2 l2e,
                                            float4* pool, int& cur) {
    const float4* Tp4 = reinterpret_cast<const float4*>(Tph);
    for (int p = 0; p < NPAIRS; ++p) {
        float4* dst = pool + (cur ^ 1) * PAIRBUF;
        if (p + 1 < NPAIRS) {
            const float4* src = Tp4 + (size_t)(p + 1) * (2 * NC * 64);
#pragma unroll
            for (int q = 0; q < 2 * NC; ++q)
                if ((q & 3) == w) gl2lds16(src + q * 64 + lane, dst + q * 64 + lane);
        } else if constexpr (NNC2 > 0) {
            const float4* src = reinterpret_cast<const float4*>(Tnext);
#pragma unroll
            for (int q = 0; q < NNC2; ++q)
                if ((q & 3) == w) gl2lds16(src + q * 64 + lane, dst + q * 64 + lane);
        }
        const float4* buf = pool + cur * PAIRBUF;
        layer_from_lds<K, NC>(h, buf, 0, lane, l2e);
        layer_from_lds<K, NC>(h, buf, 1, lane, l2e);
        __syncthreads();                              // prefetch landed (vmcnt drain)
        cur ^= 1;
    }
}

// ---- wave-local state repack KA -> KB (per-wave scratch; no barrier) ----
template<int KA, int KB>
__device__ __forceinline__ void repack_w(float2 (&a)[KA], float2 (&n)[KB],
                                         float2* scratch, int lane) {
#pragma unroll
    for (int i = 0; i < KA; ++i) scratch[KA * lane + i] = a[i];
    asm volatile("s_waitcnt lgkmcnt(0)" ::: "memory");
    __builtin_amdgcn_sched_barrier(0);
#pragma unroll
    for (int i = 0; i < KB; ++i) n[i] = scratch[KB * lane + i];
    asm volatile("s_waitcnt lgkmcnt(0)" ::: "memory");
    __builtin_amdgcn_sched_barrier(0);
}

// ---- biased 3-tap layer, K=5 layout, zero-padded ends (wave-local) ----
__device__ __forceinline__ void stage2_pk(float2 (&h)[5], const float* __restrict__ Ws,
                                          const float* __restrict__ bs, int lane) {
#pragma unroll
    for (int i = 0; i < 5; ++i)
        if (5 * lane + i > 255) h[i] = make_float2(0.f, 0.f);
    float w0[5], w1[5], w2[5], bb[5];
#pragma unroll
    for (int i = 0; i < 5; ++i) {
        int j = 5 * lane + i;
        bool v = j < 256;
        w0[i] = v ? Ws[3 * j + 0] : 0.f;
        w1[i] = v ? Ws[3 * j + 1] : 0.f;
        w2[i] = v ? Ws[3 * j + 2] : 0.f;
        bb[i] = v ? bs[j] : 0.f;
    }
    float2 p, q;
    p.x = __shfl_up(h[4].x, 1); p.y = __shfl_up(h[4].y, 1);
    if (lane == 0) p = make_float2(0.f, 0.f);
    q.x = __shfl_down(h[0].x, 1); q.y = __shfl_down(h[0].y, 1);
    float2 y[5];
#pragma unroll
    for (int i = 0; i < 5; ++i) {
        float2 xm = (i == 0) ? p : h[i - 1];
        float2 xp = (i == 4) ? q : h[i + 1];
        float ax = fmaf(xm.x, w0[i], fmaf(h[i].x, w1[i], fmaf(xp.x, w2[i], bb[i])));
        float ay = fmaf(xm.y, w0[i], fmaf(h[i].y, w1[i], fmaf(xp.y, w2[i], bb[i])));
        y[i].x = elu_f(ax);
        y[i].y = elu_f(ay);
    }
#pragma unroll
    for (int i = 0; i < 5; ++i) h[i] = y[i];
}

// ---- final 10 logits + log-softmax (K=1: position = lane; wave-local) ----
__device__ __forceinline__ void emit_row(float v, const float* __restrict__ Wl,
                                         float* __restrict__ out, int row, int lane) {
    float n1 = __shfl_down(v, 1);
    float n2 = __shfl_down(v, 2);
    float lg = 0.0f;
    if (lane < 10)
        lg = fmaf(v, Wl[3 * lane], fmaf(n1, Wl[3 * lane + 1], n2 * Wl[3 * lane + 2]));
    float t = (lane < 10) ? lg : -1e30f;
#pragma unroll
    for (int d = 1; d < 16; d <<= 1) t = fmaxf(t, __shfl_xor(t, d));
    float e = (lane < 10) ? __expf(lg - t) : 0.0f;
    float s = e;
#pragma unroll
    for (int d = 1; d < 16; d <<= 1) s += __shfl_xor(s, d);
    float lse = t + __logf(s);
    if (lane < 10) out[(size_t)row * 10 + lane] = lg - lse;
}

// ---- transposed-weight layout (floats), fine-K ladder (same as r11) ----
//  ph  K NC  l0  nl  base          (scan1: W0 lstride 2346; scan2: W2 762)
//  0  13 10   0   7  0
//  1  12  9   7  32  17920
//  2  11  9  39  32  91648
//  3  10  8  71  32  165376
//  4   9  7 103  32  230912
//  5   8  6 135  32  288256
//  6   7  6 167  32  337408
//  7   6  5 199  32  386560
//  8   5  4 231  32  427520
//  9   4  3   0  31  460288
// 10   3  3  31  32  484096
// 11   2  2  63  32  508672
// 12   1  1  95  26  525056
#define T_TOTAL 531712
#define T_ALLOC (T_TOTAL + 512)

__global__ __launch_bounds__(256)
void reorder_w(const float* __restrict__ W0, const float* __restrict__ W2,
               float* __restrict__ T) {
    int idx = blockIdx.x * 256 + threadIdx.x;
    if (idx >= T_ALLOC) return;
    if (idx >= T_TOTAL) { T[idx] = 0.0f; return; }
    int base, l0, K, NC, s1;
    if      (idx < 17920)  { base = 0;      l0 = 0;   K = 13; NC = 10; s1 = 1; }
    else if (idx < 91648)  { base = 17920;  l0 = 7;   K = 12; NC = 9;  s1 = 1; }
    else if (idx < 165376) { base = 91648;  l0 = 39;  K = 11; NC = 9;  s1 = 1; }
    else if (idx < 230912) { base = 165376; l0 = 71;  K = 10; NC = 8;  s1 = 1; }
    else if (idx < 288256) { base = 230912; l0 = 103; K = 9;  NC = 7;  s1 = 1; }
    else if (idx < 337408) { base = 288256; l0 = 135; K = 8;  NC = 6;  s1 = 1; }
    else if (idx < 386560) { base = 337408; l0 = 167; K = 7;  NC = 6;  s1 = 1; }
    else if (idx < 427520) { base = 386560; l0 = 199; K = 6;  NC = 5;  s1 = 1; }
    else if (idx < 460288) { base = 427520; l0 = 231; K = 5;  NC = 4;  s1 = 1; }
    else if (idx < 484096) { base = 460288; l0 = 0;   K = 4;  NC = 3;  s1 = 0; }
    else if (idx < 508672) { base = 484096; l0 = 31;  K = 3;  NC = 3;  s1 = 0; }
    else if (idx < 525056) { base = 508672; l0 = 63;  K = 2;  NC = 2;  s1 = 0; }
    else                   { base = 525056; l0 = 95;  K = 1;  NC = 1;  s1 = 0; }
    const float* Wsrc = s1 ? W0 : W2;
    int lstride = s1 ? 2346 : 762;
    int rel  = idx - base;
    int perL = NC * 256;
    int lr   = rel / perL;
    int r2   = rel - lr * perL;
    int c    = r2 >> 8;
    int ln   = (r2 >> 2) & 63;
    int f    = r2 & 3;
    int elem = 4 * c + f;
    float v = 0.0f;
    if (elem < 3 * K) {
        int b = 3 * K * ln;
        if (b + 3 * K > lstride) b = lstride - 3 * K;
        v = Wsrc[(size_t)(l0 + lr) * lstride + b + elem];
    }
    T[idx] = v;
}

// ---- main kernel: 4 waves/block, 8 rows, pair-buffered LDS weights ----
__global__ __launch_bounds__(256, 2)
void pg_kernel_p2(const float* __restrict__ x,  const float* __restrict__ Ws,
                  const float* __restrict__ bs, const float* __restrict__ Wlast,
                  const float* __restrict__ T,  float* __restrict__ out)
{
    __shared__ float4 pool[2 * PAIRBUF];        // 36864 B weight pair-buffers
    __shared__ float2 scr[4 * 13 * 64];         // 26624 B per-wave repack scratch
    const int tid  = threadIdx.x;
    const int w    = tid >> 6;
    const int lane = tid & 63;
    const int rowA = blockIdx.x * 8 + 2 * w;
    const int rowB = rowA + 1;
    float2* scratch = scr + w * (13 * 64);
    const float2 l2e = make_float2(1.44269504088896340736f, 1.44269504088896340736f);

    float2 h13[13];
#pragma unroll
    for (int i = 0; i < 13; ++i) {
        int p = 13 * lane + i;
        h13[i].x = (p < 784) ? x[(size_t)rowA * 784 + p] : 0.0f;
        h13[i].y = (p < 784) ? x[(size_t)rowB * 784 + p] : 0.0f;
    }

    // ---- P0 direct (K=13, NC=10, 7 layers) ----
    {
        const float4* Tp = reinterpret_cast<const float4*>(T) + lane;
        for (int l = 0; l < 7; ++l) {
            float2 wr[20];
            load_wt2<10>(wr, Tp, l);
            scan_layer_pk<13>(h13, wr, l2e);
        }
    }
    // prime P1 pair0 into buf0, repack under the latency, then barrier
    {
        const float4* src = reinterpret_cast<const float4*>(T + 17920);
#pragma unroll
        for (int q = 0; q < 18; ++q)
            if ((q & 3) == w) gl2lds16(src + q * 64 + lane, pool + q * 64 + lane);
    }
    float2 h12[12]; repack_w<13, 12>(h13, h12, scratch, lane);
    __syncthreads();
    int cur = 0;

    // ---- scan 1 (263 layers) ----
    scan_phase2<12, 9, 16, 18>(T + 17920,  T + 91648,  w, lane, h12, l2e, pool, cur);
    float2 h11[11]; repack_w<12, 11>(h12, h11, scratch, lane);
    scan_phase2<11, 9, 16, 16>(T + 91648,  T + 165376, w, lane, h11, l2e, pool, cur);
    float2 h10[10]; repack_w<11, 10>(h11, h10, scratch, lane);
    scan_phase2<10, 8, 16, 14>(T + 165376, T + 230912, w, lane, h10, l2e, pool, cur);
    float2 h9[9];   repack_w<10, 9>(h10, h9, scratch, lane);
    scan_phase2<9, 7, 16, 12>(T + 230912,  T + 288256, w, lane, h9, l2e, pool, cur);
    float2 h8[8];   repack_w<9, 8>(h9, h8, scratch, lane);
    scan_phase2<8, 6, 16, 12>(T + 288256,  T + 337408, w, lane, h8, l2e, pool, cur);
    float2 h7[7];   repack_w<8, 7>(h8, h7, scratch, lane);
    scan_phase2<7, 6, 16, 10>(T + 337408,  T + 386560, w, lane, h7, l2e, pool, cur);
    float2 h6[6];   repack_w<7, 6>(h7, h6, scratch, lane);
    scan_phase2<6, 5, 16, 8>(T + 386560,   T + 427520, w, lane, h6, l2e, pool, cur);
    float2 h5[5];   repack_w<6, 5>(h6, h5, scratch, lane);
    scan_phase2<5, 4, 16, 6>(T + 427520,   T + 460288, w, lane, h5, l2e, pool, cur);

    // ---- biased layer (width 256); wave-local (P9 pair0 already in buf[cur]) ----
    stage2_pk(h5, Ws, bs, lane);

    // ---- scan 2 (121 layers) ----
    float2 h4[4];   repack_w<5, 4>(h5, h4, scratch, lane);
    scan_phase2<4, 3, 15, 6>(T + 460288,   T + 484096, w, lane, h4, l2e, pool, cur);
    {   // P9 odd layer 30: direct register load (buf[cur] holds P10 pair0)
        const float4* Tp = reinterpret_cast<const float4*>(T + 460288) + lane;
        float2 wr[6];
        load_wt2<3>(wr, Tp, 30);
        scan_layer_pk<4>(h4, wr, l2e);
    }
    float2 h3[3];   repack_w<4, 3>(h4, h3, scratch, lane);
    scan_phase2<3, 3, 16, 4>(T + 484096,   T + 508672, w, lane, h3, l2e, pool, cur);
    float2 h2[2];   repack_w<3, 2>(h3, h2, scratch, lane);
    scan_phase2<2, 2, 16, 2>(T + 508672,   T + 525056, w, lane, h2, l2e, pool, cur);
    float2 h1[1];   repack_w<2, 1>(h2, h1, scratch, lane);
    scan_phase2<1, 1, 13, 0>(T + 525056,   (const float*)0, w, lane, h1, l2e, pool, cur);

    emit_row(h1[0].x, Wlast, out, rowA, lane);
    emit_row(h1[0].y, Wlast, out, rowB, lane);
}

// ---- scalar fallback (direct gather, G=2 single-wave) if ws too small ----
template<int K>
__device__ __forceinline__ void scan_layer_s(float (&h)[K], const float (&w)[3 * K]) {
    float e0 = __shfl_down(h[0], 1);
    float e1;
    if constexpr (K >= 2) e1 = __shfl_down(h[1], 1);
    else                  e1 = __shfl_down(h[0], 2);
#pragma unroll
    for (int i = 0; i < K; ++i) {
        float x1 = (i + 1 < K) ? h[i + 1] : e0;
        float x2 = (i + 2 < K) ? h[i + 2] : ((i + 2 == K) ? e0 : e1);
        float a = fmaf(h[i], w[3 * i], fmaf(x1, w[3 * i + 1], x2 * w[3 * i + 2]));
        h[i] = elu_f(a);
    }
}
template<int K>
__device__ __forceinline__ void scan_phase_s(const float* __restrict__ W, int lstride,
                                             int l0, int l1, int lane,
                                             float (&hA)[K], float (&hB)[K]) {
    int base = 3 * K * lane;
    if (base + 3 * K > lstride) base = lstride - 3 * K;
    const float* __restrict__ Wp = W + (size_t)l0 * lstride + base;
    float wa[3 * K];
    for (int l = l0; l < l1; ++l) {
#pragma unroll
        for (int j = 0; j < 3 * K; ++j) wa[j] = Wp[j];
        scan_layer_s<K>(hA, wa);
        scan_layer_s<K>(hB, wa);
        Wp += lstride;
    }
}
template<int KA, int KB>
__device__ __forceinline__ void repack_s(float (&aA)[KA], float (&aB)[KA],
                                         float (&nA)[KB], float (&nB)[KB],
                                         float* lds, int lane) {
    __syncthreads();
#pragma unroll
    for (int i = 0; i < KA; ++i) lds[KA * lane + i] = aA[i];
    __syncthreads();
#pragma unroll
    for (int i = 0; i < KB; ++i) nA[i] = lds[KB * lane + i];
    __syncthreads();
#pragma unroll
    for (int i = 0; i < KA; ++i) lds[KA * lane + i] = aB[i];
    __syncthreads();
#pragma unroll
    for (int i = 0; i < KB; ++i) nB[i] = lds[KB * lane + i];
    __syncthreads();
}
__global__ __launch_bounds__(64)
void pg_kernel_d(const float* __restrict__ x,  const float* __restrict__ W0,
                 const float* __restrict__ Ws, const float* __restrict__ bs,
                 const float* __restrict__ W2, const float* __restrict__ Wlast,
                 float* __restrict__ out)
{
    __shared__ float lds[13 * 64];
    const int lane = threadIdx.x;
    const int rowA = blockIdx.x * 2;
    const int rowB = rowA + 1;
    float a13[13], b13[13];
#pragma unroll
    for (int i = 0; i < 13; ++i) {
        int p = 13 * lane + i;
        a13[i] = (p < 784) ? x[(size_t)rowA * 784 + p] : 0.0f;
        b13[i] = (p < 784) ? x[(size_t)rowB * 784 + p] : 0.0f;
    }
    scan_phase_s<13>(W0, 2346, 0, 71, lane, a13, b13);
    float a10[10], b10[10]; repack_s<13, 10>(a13, b13, a10, b10, lds, lane);
    scan_phase_s<10>(W0, 2346, 71, 167, lane, a10, b10);
    float a7[7], b7[7];     repack_s<10, 7>(a10, b10, a7, b7, lds, lane);
    scan_phase_s<7>(W0, 2346, 167, 231, lane, a7, b7);
    float a5[5], b5[5];     repack_s<7, 5>(a7, b7, a5, b5, lds, lane);
    scan_phase_s<5>(W0, 2346, 231, 263, lane, a5, b5);
    {
        float2 hp[5];
#pragma unroll
        for (int i = 0; i < 5; ++i) hp[i] = make_float2(a5[i], b5[i]);
        stage2_pk(hp, Ws, bs, lane);
#pragma unroll
        for (int i = 0; i < 5; ++i) { a5[i] = hp[i].x; b5[i] = hp[i].y; }
    }
    float a4[4], b4[4];     repack_s<5, 4>(a5, b5, a4, b4, lds, lane);
    scan_phase_s<4>(W2, 762, 0, 31, lane, a4, b4);
    float a3[3], b3[3];     repack_s<4, 3>(a4, b4, a3, b3, lds, lane);
    scan_phase_s<3>(W2, 762, 31, 63, lane, a3, b3);
    float a2_[2], b2_[2];   repack_s<3, 2>(a3, b3, a2_, b2_, lds, lane);
    scan_phase_s<2>(W2, 762, 63, 95, lane, a2_, b2_);
    float a1[1], b1[1];     repack_s<2, 1>(a2_, b2_, a1, b1, lds, lane);
    scan_phase_s<1>(W2, 762, 95, 121, lane, a1, b1);
    emit_row(a1[0], Wlast, out, rowA, lane);
    emit_row(b1[0], Wlast, out, rowB, lane);
}

extern "C" void kernel_launch(void* const* d_in, const int* in_sizes, int n_in,
                              void* d_out, int out_size, void* d_ws, size_t ws_size,
                              hipStream_t stream) {
    const float* x     = (const float*)d_in[0];
    const float* W0    = (const float*)d_in[1];
    const float* Ws    = (const float*)d_in[2];
    const float* bs    = (const float*)d_in[3];
    const float* W2    = (const float*)d_in[4];
    const float* Wlast = (const float*)d_in[5];
    float* out = (float*)d_out;

    if (ws_size >= (size_t)T_ALLOC * sizeof(float)) {
        float* T = (float*)d_ws;
        reorder_w<<<(T_ALLOC + 255) / 256, 256, 0, stream>>>(W0, W2, T);
        pg_kernel_p2<<<512, 256, 0, stream>>>(x, Ws, bs, Wlast, T, out);
    } else {
        pg_kernel_d<<<2048, 64, 0, stream>>>(x, W0, Ws, bs, W2, Wlast, out);
    }
}

// Round 23
// 236.919 us; speedup vs baseline: 1.1112x; 1.1112x over previous
//
#include <hip/hip_runtime.h>
#include <math.h>

// PerceptronGlia FINAL (= r21, session best: 237us, absmax 0.0156).
// One 64-thread block (1 wave) owns 2 rows packed as float2 (A=.x, B=.y).
// Lane l owns K consecutive positions; K shrinks at every 64-width boundary
// (13x7,12,11,...,5 x32 for scan-1; 4,3,2,1 for scan-2) with wave-local LDS
// repacks. 3-tap dot via v_pk_fma_f32 with op_sel weight broadcast; depth-3
// unconditional weight ring; weights pre-transposed to d_ws (coalesced
// float4 loads). launch_bounds(64,2) licenses full VGPR (grid-limited
// occupancy anyway). 18 experiments confirmed this as the structural floor:
// per-layer weight-load latency cannot be register-pipelined (GCN scheduler
// sinks loads across asm compute; VGPR pinned ~72 in 4 attempts) and LDS
// staging costs more (conflicts+barriers) than it hides (r17/r20/r22).

#define G 2

// ---- packed-FP32 asm helpers (weight broadcast via op_sel) ----
template<int HI>
__device__ __forceinline__ float2 pk_mul_b(float2 a, float2 w) {
    float2 d;
    if constexpr (HI)
        asm("v_pk_mul_f32 %0, %1, %2 op_sel:[0,1] op_sel_hi:[1,1]"
            : "=v"(d) : "v"(a), "v"(w));
    else
        asm("v_pk_mul_f32 %0, %1, %2 op_sel_hi:[1,0]"
            : "=v"(d) : "v"(a), "v"(w));
    return d;
}
template<int HI>
__device__ __forceinline__ float2 pk_fma_b(float2 a, float2 w, float2 c) {
    float2 d;
    if constexpr (HI)
        asm("v_pk_fma_f32 %0, %1, %2, %3 op_sel:[0,1,0] op_sel_hi:[1,1,1]"
            : "=v"(d) : "v"(a), "v"(w), "v"(c));
    else
        asm("v_pk_fma_f32 %0, %1, %2, %3 op_sel_hi:[1,0,1]"
            : "=v"(d) : "v"(a), "v"(w), "v"(c));
    return d;
}
__device__ __forceinline__ float2 pk_mul2(float2 a, float2 b) {
    float2 d;
    asm("v_pk_mul_f32 %0, %1, %2" : "=v"(d) : "v"(a), "v"(b));
    return d;
}
__device__ __forceinline__ float vexp2(float x) {   // 2^x on TRANS pipe
    float d;
    asm("v_exp_f32 %0, %1" : "=v"(d) : "v"(x));
    return d;
}

__device__ __forceinline__ float elu_f(float a) {
    return a > 0.0f ? a : (__expf(a) - 1.0f);
}

// ---- one slot of a scan layer, both rows packed; static recursion ----
template<int K, int I, int NW>
__device__ __forceinline__ void slot_run(float2 (&h)[K], const float2 (&w)[NW],
                                         float2 e0, float2 e1, float2 l2e) {
    if constexpr (I < K) {
        float2 x1, x2;
        if constexpr (I + 1 < K) x1 = h[I + 1]; else x1 = e0;
        if constexpr (I + 2 < K) x2 = h[I + 2];
        else if constexpr (I + 2 == K) x2 = e0;
        else x2 = e1;
        float2 acc = pk_mul_b<(3 * I + 2) & 1>(x2, w[(3 * I + 2) >> 1]);
        acc = pk_fma_b<(3 * I + 1) & 1>(x1, w[(3 * I + 1) >> 1], acc);
        acc = pk_fma_b<(3 * I) & 1>(h[I], w[(3 * I) >> 1], acc);
        float2 t = pk_mul2(acc, l2e);                 // a * log2(e)
        float ex = vexp2(t.x) - 1.0f;
        float ey = vexp2(t.y) - 1.0f;
        h[I].x = acc.x > 0.0f ? acc.x : ex;
        h[I].y = acc.y > 0.0f ? acc.y : ey;
        slot_run<K, I + 1, NW>(h, w, e0, e1, l2e);
    }
}

template<int K, int NW>
__device__ __forceinline__ void scan_layer_pk(float2 (&h)[K], const float2 (&w)[NW],
                                              float2 l2e) {
    float2 e0, e1;
    e0.x = __shfl_down(h[0].x, 1); e0.y = __shfl_down(h[0].y, 1);
    if constexpr (K >= 2) { e1.x = __shfl_down(h[1].x, 1); e1.y = __shfl_down(h[1].y, 1); }
    else                  { e1.x = __shfl_down(h[0].x, 2); e1.y = __shfl_down(h[0].y, 2); }
    slot_run<K, 0, NW>(h, w, e0, e1, l2e);
}

// ---- transposed-weight load: NC float4 -> 2*NC float2 pairs ----
template<int NC>
__device__ __forceinline__ void load_wt2(float2 (&w)[2 * NC], const float4* __restrict__ Tp,
                                         int lr) {
#pragma unroll
    for (int c = 0; c < NC; ++c) {
        float4 v = Tp[(size_t)lr * (NC * 64) + c * 64];
        w[2 * c]     = make_float2(v.x, v.y);
        w[2 * c + 1] = make_float2(v.z, v.w);
    }
}

// ---- scan phase: depth-3 ring, UNCONDITIONAL prefetch (reads may overshoot
//      <=2 layers past the phase end -- in-bounds garbage, never consumed) ----
template<int K, int NC, int NL>
__device__ __forceinline__ void scan_phase_pk(const float* __restrict__ Tphase,
                                              int lane, float2 (&h)[K], float2 l2e) {
    static_assert(NL >= 3, "ring needs >=3 layers");
    const float4* __restrict__ Tp = reinterpret_cast<const float4*>(Tphase) + lane;
    float2 w0[2 * NC], w1[2 * NC], w2[2 * NC];
    load_wt2<NC>(w0, Tp, 0);
    load_wt2<NC>(w1, Tp, 1);
    load_wt2<NC>(w2, Tp, 2);
    int l = 0;
    for (; l + 3 <= NL; l += 3) {
        scan_layer_pk<K>(h, w0, l2e);  load_wt2<NC>(w0, Tp, l + 3);
        scan_layer_pk<K>(h, w1, l2e);  load_wt2<NC>(w1, Tp, l + 4);
        scan_layer_pk<K>(h, w2, l2e);  load_wt2<NC>(w2, Tp, l + 5);
    }
    if constexpr (NL % 3 >= 1) scan_layer_pk<K>(h, w0, l2e);
    if constexpr (NL % 3 >= 2) scan_layer_pk<K>(h, w1, l2e);
}

// ---- state repack KA -> KB via wave-local LDS (both rows at once) ----
template<int KA, int KB>
__device__ __forceinline__ void repack_pk(float2 (&a)[KA], float2 (&n)[KB],
                                          float2* lds, int lane) {
    __syncthreads();
#pragma unroll
    for (int i = 0; i < KA; ++i) lds[KA * lane + i] = a[i];
    __syncthreads();
#pragma unroll
    for (int i = 0; i < KB; ++i) n[i] = lds[KB * lane + i];
    __syncthreads();
}

// ---- biased 3-tap layer, K=5 layout, zero-padded ends ----
__device__ __forceinline__ void stage2_pk(float2 (&h)[5], const float* __restrict__ Ws,
                                          const float* __restrict__ bs, int lane) {
#pragma unroll
    for (int i = 0; i < 5; ++i)
        if (5 * lane + i > 255) h[i] = make_float2(0.f, 0.f);
    float w0[5], w1[5], w2[5], bb[5];
#pragma unroll
    for (int i = 0; i < 5; ++i) {
        int j = 5 * lane + i;
        bool v = j < 256;
        w0[i] = v ? Ws[3 * j + 0] : 0.f;
        w1[i] = v ? Ws[3 * j + 1] : 0.f;
        w2[i] = v ? Ws[3 * j + 2] : 0.f;
        bb[i] = v ? bs[j] : 0.f;
    }
    float2 p, q;
    p.x = __shfl_up(h[4].x, 1); p.y = __shfl_up(h[4].y, 1);
    if (lane == 0) p = make_float2(0.f, 0.f);
    q.x = __shfl_down(h[0].x, 1); q.y = __shfl_down(h[0].y, 1);
    float2 y[5];
#pragma unroll
    for (int i = 0; i < 5; ++i) {
        float2 xm = (i == 0) ? p : h[i - 1];
        float2 xp = (i == 4) ? q : h[i + 1];
        float ax = fmaf(xm.x, w0[i], fmaf(h[i].x, w1[i], fmaf(xp.x, w2[i], bb[i])));
        float ay = fmaf(xm.y, w0[i], fmaf(h[i].y, w1[i], fmaf(xp.y, w2[i], bb[i])));
        y[i].x = elu_f(ax);
        y[i].y = elu_f(ay);
    }
#pragma unroll
    for (int i = 0; i < 5; ++i) h[i] = y[i];
}

// ---- final 10 logits + log-softmax for one row (K=1: position = lane) ----
__device__ __forceinline__ void emit_row(float v, const float* __restrict__ Wl,
                                         float* __restrict__ out, int row, int lane) {
    float n1 = __shfl_down(v, 1);
    float n2 = __shfl_down(v, 2);
    float lg = 0.0f;
    if (lane < 10)
        lg = fmaf(v, Wl[3 * lane], fmaf(n1, Wl[3 * lane + 1], n2 * Wl[3 * lane + 2]));
    float t = (lane < 10) ? lg : -1e30f;
#pragma unroll
    for (int d = 1; d < 16; d <<= 1) t = fmaxf(t, __shfl_xor(t, d));
    float e = (lane < 10) ? __expf(lg - t) : 0.0f;
    float s = e;
#pragma unroll
    for (int d = 1; d < 16; d <<= 1) s += __shfl_xor(s, d);
    float lse = t + __logf(s);
    if (lane < 10) out[(size_t)row * 10 + lane] = lg - lse;
}

// ---- transposed-weight layout (floats), fine-K ladder ----
//  ph  K NC  l0  nl  base          (scan1: W0 lstride 2346; scan2: W2 762)
//  0  13 10   0   7  0
//  1  12  9   7  32  17920
//  2  11  9  39  32  91648
//  3  10  8  71  32  165376
//  4   9  7 103  32  230912
//  5   8  6 135  32  288256
//  6   7  6 167  32  337408
//  7   6  5 199  32  386560
//  8   5  4 231  32  427520
//  9   4  3   0  31  460288
// 10   3  3  31  32  484096
// 11   2  2  63  32  508672
// 12   1  1  95  26  525056
#define T_TOTAL 531712   // floats written; alloc +512 pad for ring overshoot
#define T_ALLOC (T_TOTAL + 512)

__global__ __launch_bounds__(256)
void reorder_w(const float* __restrict__ W0, const float* __restrict__ W2,
               float* __restrict__ T) {
    int idx = blockIdx.x * 256 + threadIdx.x;
    if (idx >= T_ALLOC) return;
    if (idx >= T_TOTAL) { T[idx] = 0.0f; return; }   // pad: benign values
    int base, l0, K, NC, s1;
    if      (idx < 17920)  { base = 0;      l0 = 0;   K = 13; NC = 10; s1 = 1; }
    else if (idx < 91648)  { base = 17920;  l0 = 7;   K = 12; NC = 9;  s1 = 1; }
    else if (idx < 165376) { base = 91648;  l0 = 39;  K = 11; NC = 9;  s1 = 1; }
    else if (idx < 230912) { base = 165376; l0 = 71;  K = 10; NC = 8;  s1 = 1; }
    else if (idx < 288256) { base = 230912; l0 = 103; K = 9;  NC = 7;  s1 = 1; }
    else if (idx < 337408) { base = 288256; l0 = 135; K = 8;  NC = 6;  s1 = 1; }
    else if (idx < 386560) { base = 337408; l0 = 167; K = 7;  NC = 6;  s1 = 1; }
    else if (idx < 427520) { base = 386560; l0 = 199; K = 6;  NC = 5;  s1 = 1; }
    else if (idx < 460288) { base = 427520; l0 = 231; K = 5;  NC = 4;  s1 = 1; }
    else if (idx < 484096) { base = 460288; l0 = 0;   K = 4;  NC = 3;  s1 = 0; }
    else if (idx < 508672) { base = 484096; l0 = 31;  K = 3;  NC = 3;  s1 = 0; }
    else if (idx < 525056) { base = 508672; l0 = 63;  K = 2;  NC = 2;  s1 = 0; }
    else                   { base = 525056; l0 = 95;  K = 1;  NC = 1;  s1 = 0; }
    const float* Wsrc = s1 ? W0 : W2;
    int lstride = s1 ? 2346 : 762;
    int rel  = idx - base;
    int perL = NC * 256;
    int lr   = rel / perL;
    int r2   = rel - lr * perL;
    int c    = r2 >> 8;
    int ln   = (r2 >> 2) & 63;
    int f    = r2 & 3;
    int elem = 4 * c + f;
    float v = 0.0f;
    if (elem < 3 * K) {
        int b = 3 * K * ln;
        if (b + 3 * K > lstride) b = lstride - 3 * K;  // clamped lanes are all-dead
        v = Wsrc[(size_t)(l0 + lr) * lstride + b + elem];
    }
    T[idx] = v;
}

// ---- main kernel (packed, depth-3 ring) ----
__global__ __launch_bounds__(64, 2)
void pg_kernel_pk(const float* __restrict__ x,  const float* __restrict__ Ws,
                  const float* __restrict__ bs, const float* __restrict__ Wlast,
                  const float* __restrict__ T,  float* __restrict__ out)
{
    __shared__ float2 lds2[13 * 64];        // repack scratch, 6.5 KB
    const int lane = threadIdx.x;
    const int rowA = blockIdx.x * G;
    const int rowB = rowA + 1;
    const float2 l2e = make_float2(1.44269504088896340736f, 1.44269504088896340736f);

    float2 h13[13];
#pragma unroll
    for (int i = 0; i < 13; ++i) {
        int p = 13 * lane + i;
        h13[i].x = (p < 784) ? x[(size_t)rowA * 784 + p] : 0.0f;
        h13[i].y = (p < 784) ? x[(size_t)rowB * 784 + p] : 0.0f;
    }

    // ---- scan 1 (263 layers) ----
    scan_phase_pk<13, 10, 7>(T + 0,       lane, h13, l2e);
    float2 h12[12]; repack_pk<13, 12>(h13, h12, lds2, lane);
    scan_phase_pk<12, 9, 32>(T + 17920,   lane, h12, l2e);
    float2 h11[11]; repack_pk<12, 11>(h12, h11, lds2, lane);
    scan_phase_pk<11, 9, 32>(T + 91648,   lane, h11, l2e);
    float2 h10[10]; repack_pk<11, 10>(h11, h10, lds2, lane);
    scan_phase_pk<10, 8, 32>(T + 165376,  lane, h10, l2e);
    float2 h9[9];   repack_pk<10, 9>(h10, h9, lds2, lane);
    scan_phase_pk<9, 7, 32>(T + 230912,   lane, h9, l2e);
    float2 h8[8];   repack_pk<9, 8>(h9, h8, lds2, lane);
    scan_phase_pk<8, 6, 32>(T + 288256,   lane, h8, l2e);
    float2 h7[7];   repack_pk<8, 7>(h8, h7, lds2, lane);
    scan_phase_pk<7, 6, 32>(T + 337408,   lane, h7, l2e);
    float2 h6[6];   repack_pk<7, 6>(h7, h6, lds2, lane);
    scan_phase_pk<6, 5, 32>(T + 386560,   lane, h6, l2e);
    float2 h5[5];   repack_pk<6, 5>(h6, h5, lds2, lane);
    scan_phase_pk<5, 4, 32>(T + 427520,   lane, h5, l2e);

    // ---- biased layer (width 256) ----
    stage2_pk(h5, Ws, bs, lane);

    // ---- scan 2 (121 layers) ----
    float2 h4[4];   repack_pk<5, 4>(h5, h4, lds2, lane);
    scan_phase_pk<4, 3, 31>(T + 460288,   lane, h4, l2e);
    float2 h3[3];   repack_pk<4, 3>(h4, h3, lds2, lane);
    scan_phase_pk<3, 3, 32>(T + 484096,   lane, h3, l2e);
    float2 h2[2];   repack_pk<3, 2>(h3, h2, lds2, lane);
    scan_phase_pk<2, 2, 32>(T + 508672,   lane, h2, l2e);
    float2 h1[1];   repack_pk<2, 1>(h2, h1, lds2, lane);
    scan_phase_pk<1, 1, 26>(T + 525056,   lane, h1, l2e);

    emit_row(h1[0].x, Wlast, out, rowA, lane);
    emit_row(h1[0].y, Wlast, out, rowB, lane);
}

// ---- scalar fallback (direct gather) used only if ws too small ----
template<int K>
__device__ __forceinline__ void scan_layer_s(float (&h)[K], const float (&w)[3 * K]) {
    float e0 = __shfl_down(h[0], 1);
    float e1;
    if constexpr (K >= 2) e1 = __shfl_down(h[1], 1);
    else                  e1 = __shfl_down(h[0], 2);
#pragma unroll
    for (int i = 0; i < K; ++i) {
        float x1 = (i + 1 < K) ? h[i + 1] : e0;
        float x2 = (i + 2 < K) ? h[i + 2] : ((i + 2 == K) ? e0 : e1);
        float a = fmaf(h[i], w[3 * i], fmaf(x1, w[3 * i + 1], x2 * w[3 * i + 2]));
        h[i] = elu_f(a);
    }
}
template<int K>
__device__ __forceinline__ void scan_phase_s(const float* __restrict__ W, int lstride,
                                             int l0, int l1, int lane,
                                             float (&hA)[K], float (&hB)[K]) {
    int base = 3 * K * lane;
    if (base + 3 * K > lstride) base = lstride - 3 * K;
    const float* __restrict__ Wp = W + (size_t)l0 * lstride + base;
    float wa[3 * K];
    for (int l = l0; l < l1; ++l) {
#pragma unroll
        for (int j = 0; j < 3 * K; ++j) wa[j] = Wp[j];
        scan_layer_s<K>(hA, wa);
        scan_layer_s<K>(hB, wa);
        Wp += lstride;
    }
}
template<int KA, int KB>
__device__ __forceinline__ void repack_s(float (&aA)[KA], float (&aB)[KA],
                                         float (&nA)[KB], float (&nB)[KB],
                                         float* lds, int lane) {
    __syncthreads();
#pragma unroll
    for (int i = 0; i < KA; ++i) lds[KA * lane + i] = aA[i];
    __syncthreads();
#pragma unroll
    for (int i = 0; i < KB; ++i) nA[i] = lds[KB * lane + i];
    __syncthreads();
#pragma unroll
    for (int i = 0; i < KA; ++i) lds[KA * lane + i] = aB[i];
    __syncthreads();
#pragma unroll
    for (int i = 0; i < KB; ++i) nB[i] = lds[KB * lane + i];
    __syncthreads();
}
__global__ __launch_bounds__(64)
void pg_kernel_d(const float* __restrict__ x,  const float* __restrict__ W0,
                 const float* __restrict__ Ws, const float* __restrict__ bs,
                 const float* __restrict__ W2, const float* __restrict__ Wlast,
                 float* __restrict__ out)
{
    __shared__ float lds[13 * 64];
    const int lane = threadIdx.x;
    const int rowA = blockIdx.x * 2;
    const int rowB = rowA + 1;
    float a13[13], b13[13];
#pragma unroll
    for (int i = 0; i < 13; ++i) {
        int p = 13 * lane + i;
        a13[i] = (p < 784) ? x[(size_t)rowA * 784 + p] : 0.0f;
        b13[i] = (p < 784) ? x[(size_t)rowB * 784 + p] : 0.0f;
    }
    scan_phase_s<13>(W0, 2346, 0, 71, lane, a13, b13);
    float a10[10], b10[10]; repack_s<13, 10>(a13, b13, a10, b10, lds, lane);
    scan_phase_s<10>(W0, 2346, 71, 167, lane, a10, b10);
    float a7[7], b7[7];     repack_s<10, 7>(a10, b10, a7, b7, lds, lane);
    scan_phase_s<7>(W0, 2346, 167, 231, lane, a7, b7);
    float a5[5], b5[5];     repack_s<7, 5>(a7, b7, a5, b5, lds, lane);
    scan_phase_s<5>(W0, 2346, 231, 263, lane, a5, b5);
    {
        float2 hp[5];
#pragma unroll
        for (int i = 0; i < 5; ++i) hp[i] = make_float2(a5[i], b5[i]);
        stage2_pk(hp, Ws, bs, lane);
#pragma unroll
        for (int i = 0; i < 5; ++i) { a5[i] = hp[i].x; b5[i] = hp[i].y; }
    }
    float a4[4], b4[4];     repack_s<5, 4>(a5, b5, a4, b4, lds, lane);
    scan_phase_s<4>(W2, 762, 0, 31, lane, a4, b4);
    float a3[3], b3[3];     repack_s<4, 3>(a4, b4, a3, b3, lds, lane);
    scan_phase_s<3>(W2, 762, 31, 63, lane, a3, b3);
    float a2_[2], b2_[2];   repack_s<3, 2>(a3, b3, a2_, b2_, lds, lane);
    scan_phase_s<2>(W2, 762, 63, 95, lane, a2_, b2_);
    float a1[1], b1[1];     repack_s<2, 1>(a2_, b2_, a1, b1, lds, lane);
    scan_phase_s<1>(W2, 762, 95, 121, lane, a1, b1);
    emit_row(a1[0], Wlast, out, rowA, lane);
    emit_row(b1[0], Wlast, out, rowB, lane);
}

extern "C" void kernel_launch(void* const* d_in, const int* in_sizes, int n_in,
                              void* d_out, int out_size, void* d_ws, size_t ws_size,
                              hipStream_t stream) {
    const float* x     = (const float*)d_in[0];
    const float* W0    = (const float*)d_in[1];
    const float* Ws    = (const float*)d_in[2];
    const float* bs    = (const float*)d_in[3];
    const float* W2    = (const float*)d_in[4];
    const float* Wlast = (const float*)d_in[5];
    float* out = (float*)d_out;

    if (ws_size >= (size_t)T_ALLOC * sizeof(float)) {
        float* T = (float*)d_ws;
        reorder_w<<<(T_ALLOC + 255) / 256, 256, 0, stream>>>(W0, W2, T);
        pg_kernel_pk<<<4096 / G, 64, 0, stream>>>(x, Ws, bs, Wlast, T, out);
    } else {
        pg_kernel_d<<<2048, 64, 0, stream>>>(x, W0, Ws, bs, W2, Wlast, out);
    }
}